// Round 6
// baseline (639.634 us; speedup 1.0000x reference)
//
#include <hip/hip_runtime.h>
#include <hip/hip_bf16.h>
#include <stdint.h>

typedef __bf16 bf16_t;
typedef __attribute__((ext_vector_type(8))) __bf16 bf16x8;
typedef __attribute__((ext_vector_type(4))) __bf16 bf16x4;
typedef __attribute__((ext_vector_type(16))) float f32x16;

constexpr int IN_F   = 4096;
constexpr int OUT_F  = 4096;
constexpr int RANKC  = 12;
constexpr float SCAL = 16.0f / 12.0f;
constexpr int MTOT   = 4 * 4096;   // B*S = 16384
constexpr int NT     = IN_F / 64;  // 64 K-tiles

typedef __attribute__((address_space(1))) const unsigned int uint_g;
typedef __attribute__((address_space(3))) unsigned int uint_l;

__device__ __forceinline__ void gload_lds16(const void* g, void* l) {
    __builtin_amdgcn_global_load_lds((uint_g*)(uintptr_t)g,
                                     (uint_l*)(uintptr_t)l,
                                     16, 0, 0);
}

// ---------------------------------------------------------------------------
// Kernel 1: Wb[o,i] = bf16( W[o,i] + SCAL * sum_r P[o,r]*sigma[r]*Q[i,r] )
// ---------------------------------------------------------------------------
__global__ __launch_bounds__(256) void fold_weight_kernel(
    const float* __restrict__ W, const float* __restrict__ P,
    const float* __restrict__ sg, const float* __restrict__ Q,
    bf16_t* __restrict__ Wb)
{
    const int t    = blockIdx.x * 256 + threadIdx.x;
    const int base = t * 4;
    const int o    = base >> 12;
    const int i0   = base & (IN_F - 1);

    float psig[RANKC];
#pragma unroll
    for (int r = 0; r < RANKC; ++r)
        psig[r] = P[o * RANKC + r] * sg[r] * SCAL;

    const float4 w = *reinterpret_cast<const float4*>(W + base);
    float out[4] = {w.x, w.y, w.z, w.w};
#pragma unroll
    for (int j = 0; j < 4; ++j) {
        const float* q = Q + (size_t)(i0 + j) * RANKC;
        float d = 0.0f;
#pragma unroll
        for (int r = 0; r < RANKC; ++r) d += psig[r] * q[r];
        out[j] += d;
    }
    bf16x4 ob;
#pragma unroll
    for (int j = 0; j < 4; ++j) ob[j] = (bf16_t)out[j];
    *reinterpret_cast<bf16x4*>(Wb + base) = ob;
}

// ---------------------------------------------------------------------------
// Kernel 2: x (fp32) -> bf16
// ---------------------------------------------------------------------------
__global__ __launch_bounds__(256) void cvt_x_kernel(
    const float* __restrict__ X, bf16_t* __restrict__ Xb)
{
    const size_t base = ((size_t)blockIdx.x * 256 + threadIdx.x) * 8;
    const float4 a = *reinterpret_cast<const float4*>(X + base);
    const float4 b = *reinterpret_cast<const float4*>(X + base + 4);
    bf16x8 ob;
    ob[0] = (bf16_t)a.x; ob[1] = (bf16_t)a.y; ob[2] = (bf16_t)a.z; ob[3] = (bf16_t)a.w;
    ob[4] = (bf16_t)b.x; ob[5] = (bf16_t)b.y; ob[6] = (bf16_t)b.z; ob[7] = (bf16_t)b.w;
    *reinterpret_cast<bf16x8*>(Xb + base) = ob;
}

// ---------------------------------------------------------------------------
// Kernel 3: 256x256 4-phase pipelined GEMM, 32x32x16 MFMA, register-prefetch.
//
// Same LDS swizzle / staging map / VMW schedule as round 5 (HW-verified):
//   stages: p1 B(t+1){0,64}  p2 B(t+1){128,192}  p3 A-H1(t+1)  p4 A-H0(t+2)
//   waits:  p1 VMW(4) [drains A-H1(t)]  p2 VMW(4) [drains A-H0(t+1)]
//           p3 VMW(2) [drains B(t+1)]   p4 none
// Compute mapping (per wave: 4 tm-tiles x 2 tn-tiles of 32x32, 4 k-steps):
//   p1: kk01 x tm01 (A-H0)   p2: kk23 x tm01 (A-H0)
//   p3: kk01 x tm23 (A-H1)   p4: kk23 x tm23 (A-H1)
// Head prefetch (reads only regions drained by an EARLIER phase's VMW+BAR):
//   p1: afY<-A[tm01,kk23](CA_), bq23<-B(t)[kk23](CB_)    [resident]
//   p2: afX<-A[tm23,kk01](CA_)   [A-H1(t) drained p1 VMW(4)+BAR]
//   p3: afY<-A[tm23,kk23](CA_)   [same]
//   p4: afX<-A(t+1)[tm01,kk01](NA_) [drained p2], bq01<-B(t+1)[kk01](NB_)
//                                   [drained p3]
// A frag: row=lane&31, k=(lane>>5)*8+j  ->  chunk = kstep*2 + (lane>>5)
// C/D: col=lane&31, row=(reg&3)+8*(reg>>2)+4*(lane>>5)  [m74/m101-verified]
// ---------------------------------------------------------------------------
__device__ __forceinline__ void stage64(const bf16_t* __restrict__ g, size_t grow0,
                                        bf16_t* lt, int ldrow0, int kt, int tid)
{
    const int rr  = tid >> 3;                       // 0..63 within region
    const int c16 = (tid & 7) ^ (rr & 7);           // inverse-swizzled source chunk
    const bf16_t* src = g + (grow0 + (size_t)(ldrow0 + rr)) * IN_F + kt * 64 + c16 * 8;
    gload_lds16(src, lt + ldrow0 * 64 + tid * 8);   // linear LDS dest
}

#define VMW(N) asm volatile("s_waitcnt vmcnt(" #N ")" ::: "memory")
#define BAR    __builtin_amdgcn_s_barrier()
#define SB     __builtin_amdgcn_sched_barrier(0)

#define RD_A32(DST, BUF, TMH, KKP) do {                                         \
    _Pragma("unroll")                                                           \
    for (int tm_ = 0; tm_ < 2; ++tm_)                                           \
        _Pragma("unroll")                                                       \
        for (int kk_ = 0; kk_ < 2; ++kk_) {                                     \
            const int row_  = wm * 128 + ((TMH) * 2 + tm_) * 32 + l31;          \
            const int slot_ = (((KKP) * 2 + kk_) * 2 + l5) ^ (row_ & 7);        \
            DST[tm_ * 2 + kk_] = *(const bf16x8*)&BUF[row_ * 64 + slot_ * 8];   \
        }                                                                       \
} while (0)

#define RD_B32(DST, BUF, KKP) do {                                              \
    _Pragma("unroll")                                                           \
    for (int tn_ = 0; tn_ < 2; ++tn_)                                           \
        _Pragma("unroll")                                                       \
        for (int kk_ = 0; kk_ < 2; ++kk_) {                                     \
            const int row_  = wn * 64 + tn_ * 32 + l31;                         \
            const int slot_ = (((KKP) * 2 + kk_) * 2 + l5) ^ (row_ & 7);        \
            DST[tn_ * 2 + kk_] = *(const bf16x8*)&BUF[row_ * 64 + slot_ * 8];   \
        }                                                                       \
} while (0)

#define MM32(AF, BQ, TMH) do {                                                  \
    __builtin_amdgcn_s_setprio(1);                                              \
    _Pragma("unroll")                                                           \
    for (int tm_ = 0; tm_ < 2; ++tm_)                                           \
        _Pragma("unroll")                                                       \
        for (int tn_ = 0; tn_ < 2; ++tn_)                                       \
            _Pragma("unroll")                                                   \
            for (int kk_ = 0; kk_ < 2; ++kk_)                                   \
                acc[(TMH) * 2 + tm_][tn_] =                                     \
                    __builtin_amdgcn_mfma_f32_32x32x16_bf16(                    \
                        AF[tm_ * 2 + kk_], BQ[tn_ * 2 + kk_],                   \
                        acc[(TMH) * 2 + tm_][tn_], 0, 0, 0);                    \
    __builtin_amdgcn_s_setprio(0);                                              \
} while (0)

#define TILE(T, CA_, CB_, NA_, NB_) do {                                        \
    const int t1_ = ((T) + 1 < NT) ? (T) + 1 : NT - 1;                          \
    const int t2_ = ((T) + 2 < NT) ? (T) + 2 : NT - 1;                          \
    /* p1: consume (afX, bq01) = tm01 x kk01 */                                 \
    stage64(Bm, bcol, NB_, 0,   t1_, tid);                                      \
    stage64(Bm, bcol, NB_, 64,  t1_, tid);                                      \
    RD_A32(afY, CA_, 0, 1);                                                     \
    RD_B32(bq23, CB_, 1);                                                       \
    MM32(afX, bq01, 0);                                                         \
    VMW(4);                                                                     \
    BAR; SB;                                                                    \
    /* p2: consume (afY, bq23) = tm01 x kk23 */                                 \
    stage64(Bm, bcol, NB_, 128, t1_, tid);                                      \
    stage64(Bm, bcol, NB_, 192, t1_, tid);                                      \
    RD_A32(afX, CA_, 1, 0);                                                     \
    MM32(afY, bq23, 0);                                                         \
    VMW(4);                                                                     \
    BAR; SB;                                                                    \
    /* p3: consume (afX, bq01) = tm23 x kk01 */                                 \
    stage64(Am, brow, NA_, 64,  t1_, tid);                                      \
    stage64(Am, brow, NA_, 192, t1_, tid);                                      \
    RD_A32(afY, CA_, 1, 1);                                                     \
    MM32(afX, bq01, 1);                                                         \
    VMW(2);                                                                     \
    BAR; SB;                                                                    \
    /* p4: consume (afY, bq23) = tm23 x kk23; prefetch next tile */             \
    stage64(Am, brow, CA_, 0,   t2_, tid);                                      \
    stage64(Am, brow, CA_, 128, t2_, tid);                                      \
    RD_A32(afX, NA_, 0, 0);                                                     \
    RD_B32(bq01, NB_, 0);                                                       \
    MM32(afY, bq23, 1);                                                         \
    BAR; SB;                                                                    \
} while (0)

__global__ __launch_bounds__(512, 2) void gemm256_kernel(
    const bf16_t* __restrict__ Am,   // [MTOT, IN_F]
    const bf16_t* __restrict__ Bm,   // [OUT_F, IN_F]
    float* __restrict__ C)           // [MTOT, OUT_F]
{
    __shared__ bf16_t sA0[256 * 64], sB0[256 * 64], sA1[256 * 64], sB1[256 * 64];

    const int tid  = threadIdx.x;
    const int lane = tid & 63;
    const int l31  = lane & 31;
    const int l5   = lane >> 5;
    const int wave = tid >> 6;
    const int wm   = wave >> 2;      // 0..1
    const int wn   = wave & 3;       // 0..3

    // XCD-aware bijective swizzle (nwg = 1024, % 8 == 0)
    const int bid = blockIdx.x;
    const int swz = (bid & 7) * 128 + (bid >> 3);
    const size_t brow = (size_t)(swz >> 4) * 256;   // 64 row-blocks
    const size_t bcol = (size_t)(swz & 15) * 256;   // 16 col-blocks

    f32x16 acc[4][2];
#pragma unroll
    for (int i = 0; i < 4; ++i)
#pragma unroll
        for (int n = 0; n < 2; ++n)
#pragma unroll
            for (int q = 0; q < 16; ++q) acc[i][n][q] = 0.0f;

    bf16x8 bq01[4], bq23[4];
    bf16x8 afX[4], afY[4];

    // Prologue: drain A-H0(0)+B(0) with VMW(4); leave [A-H1(0)2, A-H0(1)2].
    stage64(Am, brow, sA0, 0,   0, tid);   // A-H0(0)
    stage64(Am, brow, sA0, 128, 0, tid);
    stage64(Bm, bcol, sB0, 0,   0, tid);   // B(0)
    stage64(Bm, bcol, sB0, 64,  0, tid);
    stage64(Bm, bcol, sB0, 128, 0, tid);
    stage64(Bm, bcol, sB0, 192, 0, tid);
    stage64(Am, brow, sA0, 64,  0, tid);   // A-H1(0)
    stage64(Am, brow, sA0, 192, 0, tid);
    stage64(Am, brow, sA1, 0,   1, tid);   // A-H0(1)
    stage64(Am, brow, sA1, 128, 1, tid);
    VMW(4);
    BAR; SB;
    // initial fragments for p1(0) (regions drained above, post-BAR)
    RD_A32(afX, sA0, 0, 0);
    RD_B32(bq01, sB0, 0);

    for (int tt = 0; tt < NT; tt += 2) {
        TILE(tt,     sA0, sB0, sA1, sB1);
        TILE(tt + 1, sA1, sB1, sA0, sB0);
    }

    // Epilogue: col = lane&31, row = (reg&3)+8*(reg>>2)+4*(lane>>5)
    const size_t c0 = bcol + (size_t)wn * 64 + l31;
    const size_t rb = brow + (size_t)wm * 128 + 4 * l5;
#pragma unroll
    for (int tm = 0; tm < 4; ++tm)
#pragma unroll
        for (int tn = 0; tn < 2; ++tn)
#pragma unroll
            for (int rg = 0; rg < 16; ++rg) {
                const size_t row = rb + tm * 32 + (rg & 3) + 8 * (rg >> 2);
                C[row * OUT_F + c0 + tn * 32] = acc[tm][tn][rg];
            }
}

// ---------------------------------------------------------------------------
extern "C" void kernel_launch(void* const* d_in, const int* in_sizes, int n_in,
                              void* d_out, int out_size, void* d_ws, size_t ws_size,
                              hipStream_t stream)
{
    const float* x      = (const float*)d_in[0];
    const float* weight = (const float*)d_in[1];
    const float* loraP  = (const float*)d_in[2];
    const float* sigma  = (const float*)d_in[3];
    const float* loraQ  = (const float*)d_in[4];
    float* out = (float*)d_out;

    bf16_t* Wb = (bf16_t*)d_ws;                                      // 32 MiB
    bf16_t* Xb = (bf16_t*)((char*)d_ws + (size_t)OUT_F * IN_F * 2);  // 128 MiB

    fold_weight_kernel<<<(OUT_F * IN_F) / (256 * 4), 256, 0, stream>>>(
        weight, loraP, sigma, loraQ, Wb);

    cvt_x_kernel<<<((size_t)MTOT * IN_F) / (256 * 8), 256, 0, stream>>>(x, Xb);

    gemm256_kernel<<<(MTOT / 256) * (OUT_F / 256), 512, 0, stream>>>(Xb, Wb, out);
}